// Round 12
// baseline (23040.709 us; speedup 1.0000x reference)
//
#include <hip/hip_runtime.h>

// Problem dims
#define TT   512
#define BB   256
#define OBSD 256
#define DD   512
#define HH   512
#define MROWS (TT*BB)   // 131072

typedef __attribute__((ext_vector_type(8))) short short8;
typedef __attribute__((ext_vector_type(4))) float f32x4;

__device__ __forceinline__ ushort f2b(float f){
  unsigned int x = __float_as_uint(f);
  x = (x + 0x7fffu + ((x >> 16) & 1u)) >> 16;   // RNE
  return (ushort)x;
}
__device__ __forceinline__ float b2f(ushort u){
  return __uint_as_float(((unsigned int)u) << 16);
}
__device__ __forceinline__ float sigm(float x){ return 1.f/(1.f + __expf(-x)); }
__device__ __forceinline__ float tanh_f(float x){ return 1.f - 2.f/(__expf(2.f*x) + 1.f); }

// ---------------- transpose f32 [K,N] -> bf16 [N,K] ----------------
__global__ void k_transpose_bf16(const float* __restrict__ W, ushort* __restrict__ Wt,
                                 int K, int N){
  int i = blockIdx.x*256 + threadIdx.x;
  if(i >= K*N) return;
  int k = i / N, n = i % N;
  Wt[(size_t)n*K + k] = f2b(W[i]);
}

// ---------------- f32 -> bf16 elementwise (vectorized) ----------------
__global__ void k_f32_to_bf16(const float* __restrict__ in, ushort* __restrict__ out,
                              int n4){
  int i = blockIdx.x*256 + threadIdx.x;
  if(i >= n4) return;
  const float4 v = ((const float4*)in)[i];
  union{ ushort u[4]; uint2 d; } p;
  p.u[0] = f2b(v.x); p.u[1] = f2b(v.y); p.u[2] = f2b(v.z); p.u[3] = f2b(v.w);
  ((uint2*)out)[i] = p.d;
}

// ---------------- detect done dtype (byte-packed vs 4-byte) ----------------
__global__ void k_detect(const int* __restrict__ done, int* __restrict__ flag){
  __shared__ int cnt;
  if(threadIdx.x == 0) cnt = 0;
  __syncthreads();
  int c = 0;
  for(int i = threadIdx.x; i < 32768; i += 256) c += (done[i] != 0);
  for(int off = 32; off; off >>= 1) c += __shfl_down(c, off, 64);
  if((threadIdx.x & 63) == 0) atomicAdd(&cnt, c);
  __syncthreads();
  if(threadIdx.x == 0) *flag = (cnt > 700) ? 1 : 0;  // 1 => byte-packed bools
}

// ---------------- 128x128-tile MFMA GEMM, 2-phase double-buffered staging ----------------
#define GSTAGE(buf, k0v) { \
  _Pragma("unroll") \
  for(int j = 0; j < 2; j++){ \
    const int flat = tid*16 + j*4096;        /* byte offset in 8KB tile */ \
    const int rw  = flat >> 6;               /* 64B per row */ \
    const int ke  = (flat & 63) >> 1;        /* k-elem within 32 */ \
    __builtin_amdgcn_global_load_lds( \
      (const __attribute__((address_space(1))) void*)(A + (m0+rw)*(size_t)K + (k0v) + ke), \
      (__attribute__((address_space(3))) void*)((char*)As[buf] + flat), 16, 0, 0); \
    __builtin_amdgcn_global_load_lds( \
      (const __attribute__((address_space(1))) void*)(Bt + (n0+rw)*(size_t)K + (k0v) + ke), \
      (__attribute__((address_space(3))) void*)((char*)Bs[buf] + flat), 16, 0, 0); \
  } }
#define GCOMPUTE(buf) { \
    short8 af[4], bf[4]; \
    _Pragma("unroll") for(int mi=0;mi<4;mi++) \
      af[mi] = *(const short8*)((const char*)As[buf] + (wr*64+mi*16+l16)*64 + l4*16); \
    _Pragma("unroll") for(int ni=0;ni<4;ni++) \
      bf[ni] = *(const short8*)((const char*)Bs[buf] + (wc*64+ni*16+l16)*64 + l4*16); \
    _Pragma("unroll") for(int mi=0;mi<4;mi++) \
      _Pragma("unroll") for(int ni=0;ni<4;ni++) \
        acc[mi][ni] = __builtin_amdgcn_mfma_f32_16x16x32_bf16(af[mi], bf[ni], acc[mi][ni], 0,0,0); }

__global__ __launch_bounds__(256) void k_gemm128(const ushort* __restrict__ A,
                                                 const ushort* __restrict__ Bt,
                                                 const float* __restrict__ bias,
                                                 ushort* __restrict__ C,
                                                 int M, int N, int K, int relu,
                                                 int xg_layout){
  __shared__ __align__(16) ushort As[2][4096];   // 2 x 8KB
  __shared__ __align__(16) ushort Bs[2][4096];
  const int tid = threadIdx.x;
  const int l = tid & 63, l16 = l & 15, l4 = l >> 4;
  const int w = tid >> 6, wr = w >> 1, wc = w & 1;
  const size_t m0 = (size_t)blockIdx.x*128, n0 = (size_t)blockIdx.y*128;
  f32x4 acc[4][4] = {};

  GSTAGE(0, 0);
  asm volatile("s_waitcnt vmcnt(0)" ::: "memory");
  __syncthreads();
  int cur = 0;
  for(int k0 = 32; k0 < K; k0 += 32){
    GSTAGE(cur^1, k0);           // prefetch next tile while computing current
    GCOMPUTE(cur);
    asm volatile("s_waitcnt vmcnt(0)" ::: "memory");
    __syncthreads();
    cur ^= 1;
  }
  GCOMPUTE(cur);

  #pragma unroll
  for(int ni=0;ni<4;ni++){
    const int col = (int)n0 + wc*64 + ni*16 + l16;
    const float bv = bias[col];
    #pragma unroll
    for(int mi=0;mi<4;mi++){
      #pragma unroll
      for(int r=0;r<4;r++){
        const int row = (int)m0 + wr*64 + mi*16 + l4*4 + r;
        float v = acc[mi][ni][r] + bv;
        if(relu) v = fmaxf(v, 0.f);
        size_t addr;
        if(xg_layout){
          // scan-native: [t][dsp16][g8][gate3][r32][c32]
          const int tl = row >> 8, brow = row & 255;
          const int gg = brow >> 5, r32 = brow & 31;
          const int gate = col >> 9, cw = col & 511, dsp = cw >> 5, c32 = cw & 31;
          addr = ((((size_t)tl*16 + dsp)*8 + gg)*3 + gate)*1024 + r32*32 + c32;
        } else {
          addr = (size_t)row*N + col;
        }
        C[addr] = f2b(v);
      }
    }
  }
}

// ======================= cooperative GRU scan =======================
// 128 blocks x 128 thr (2 waves). Group g = bid&7 (32 batch rows), ds = bid>>3 in
// [0,16): 32 d-cols per block. 16-participant barrier (half of r11). Same-XCD fast
// path (runtime-verified). WhT slice 3 gates x 32 d = 96 KB LDS; 96 MFMA/step.
// h exchange layout [g][ds][r32][d32]: block-contiguous 2KB region per block.
__device__ __forceinline__ void bar_slow(int* cntA, int g, int ds, int target, int tid){
  asm volatile("s_waitcnt vmcnt(0)" ::: "memory");
  __syncthreads();
  if(tid == 0)
    __hip_atomic_store(cntA + g*32 + ds, target,
                       __ATOMIC_RELAXED, __HIP_MEMORY_SCOPE_AGENT);
  if(tid < 16){
    const int* fp = cntA + g*32 + tid;
    while(__hip_atomic_load(fp, __ATOMIC_RELAXED, __HIP_MEMORY_SCOPE_AGENT) < target)
      __builtin_amdgcn_s_sleep(1);
  }
  __syncthreads();
}

__device__ __forceinline__ void bar_fast(int* cntL, int* cntA, int g, int ds,
                                         int target, int tid){
  asm volatile("s_waitcnt vmcnt(0)" ::: "memory");   // h stores landed in local L2
  __syncthreads();
  if(tid == 0){
    int* pL = cntL + g*32 + ds;
    asm volatile("global_atomic_swap %0, %1, off" :: "v"(pL), "v"(target) : "memory");
    __hip_atomic_store(cntA + g*32 + ds, target,
                       __ATOMIC_RELAXED, __HIP_MEMORY_SCOPE_AGENT);   // mirror
  }
  if(tid < 16){
    int* fpL = cntL + g*32 + tid;
    const int* fpA = cntA + g*32 + tid;
    int it = 0;
    for(;;){
      int old;
      asm volatile("global_atomic_add %0, %1, %2, off sc0"
                   : "=v"(old) : "v"(fpL), "v"(0) : "memory");
      asm volatile("s_waitcnt vmcnt(0)" ::: "memory");
      if(old >= target) break;
      if((++it & 15) == 0 &&
         __hip_atomic_load(fpA, __ATOMIC_RELAXED, __HIP_MEMORY_SCOPE_AGENT) >= target)
        break;                                        // safety net: agent mirror
      __builtin_amdgcn_s_sleep(1);
    }
  }
  __syncthreads();
  asm volatile("buffer_inv sc0" ::: "memory");        // L1 invalidate before peer-h reads
}

#define ALD_S(v, j) { const ushort* pj_ = hgrp + (j)*1024; \
  asm volatile("global_load_dwordx4 %0, %1, off sc0 sc1" : "=&v"(v) : "v"(pj_)); }
#define ALD_F(v, j) { const ushort* pj_ = hgrp + (j)*1024; \
  asm volatile("global_load_dwordx4 %0, %1, off" : "=&v"(v) : "v"(pj_)); }
#define DECL_A short8 a0,a1,a2,a3,a4,a5,a6,a7,a8,a9,a10,a11,a12,a13,a14,a15
#define ALOADS(M) M(a0,0);M(a1,1);M(a2,2);M(a3,3);M(a4,4);M(a5,5);M(a6,6);M(a7,7); \
  M(a8,8);M(a9,9);M(a10,10);M(a11,11);M(a12,12);M(a13,13);M(a14,14);M(a15,15)
#define ZERO_A { const short8 z = {0,0,0,0,0,0,0,0}; \
  a0=z;a1=z;a2=z;a3=z;a4=z;a5=z;a6=z;a7=z;a8=z;a9=z;a10=z;a11=z;a12=z;a13=z;a14=z;a15=z; }
// 6 MFMA per K-chunk: 3 gates x 2 d-tiles
#define STEPK(ak, k0lit) { const int kboff = ((k0lit + l4*8) << 1); \
  _Pragma("unroll") for(int gi=0; gi<3; gi++) \
  _Pragma("unroll") for(int dt=0; dt<2; dt++){ \
    const short8 wf = *(const short8*)((const char*)whs + ((rb[gi][dt] + kboff) ^ sw[gi][dt])); \
    acc[gi][dt] = __builtin_amdgcn_mfma_f32_16x16x32_bf16(wf, ak, acc[gi][dt], 0, 0, 0); } }
#define MFMA96 STEPK(a0,0) STEPK(a1,32) STEPK(a2,64) STEPK(a3,96) STEPK(a4,128) \
  STEPK(a5,160) STEPK(a6,192) STEPK(a7,224) STEPK(a8,256) STEPK(a9,288) STEPK(a10,320) \
  STEPK(a11,352) STEPK(a12,384) STEPK(a13,416) STEPK(a14,448) STEPK(a15,480)
// xg slice = 6KB = 6 regions of 1KB; wave m stages regions m*3..m*3+2 (3 loads/wave)
#define XG_PREFETCH(tls, nb) { \
  const ushort* slb_ = xg + ((((size_t)(tls)*16 + ds)*8 + g)*3072); \
  const int q0_ = m*1536; \
  __builtin_amdgcn_global_load_lds( \
    (const __attribute__((address_space(1))) void*)(slb_ + q0_ + l*8), \
    (__attribute__((address_space(3))) void*)(&xgs[nb][q0_]), 16, 0, 0); \
  __builtin_amdgcn_global_load_lds( \
    (const __attribute__((address_space(1))) void*)(slb_ + q0_ + 512 + l*8), \
    (__attribute__((address_space(3))) void*)(&xgs[nb][q0_ + 512]), 16, 0, 0); \
  __builtin_amdgcn_global_load_lds( \
    (const __attribute__((address_space(1))) void*)(slb_ + q0_ + 1024 + l*8), \
    (__attribute__((address_space(3))) void*)(&xgs[nb][q0_ + 1024]), 16, 0, 0); }
// epilogue: 2 d-tiles x 4 outputs; xgs layout [gate3][r32][c32]
#define GRU_EPI {                                                        \
  _Pragma("unroll") for(int dt=0; dt<2; dt++){                           \
    const int xb = r32*32 + dt*16 + l4*4;                                \
    const uint2 xru = *(const uint2*)&xgs[cur][       xb];               \
    const uint2 xzu = *(const uint2*)&xgs[cur][1024 + xb];               \
    const uint2 xnu = *(const uint2*)&xgs[cur][2048 + xb];               \
    const ushort xr4[4] = {(ushort)(xru.x&0xffff),(ushort)(xru.x>>16),   \
                           (ushort)(xru.y&0xffff),(ushort)(xru.y>>16)};  \
    const ushort xz4[4] = {(ushort)(xzu.x&0xffff),(ushort)(xzu.x>>16),   \
                           (ushort)(xzu.y&0xffff),(ushort)(xzu.y>>16)};  \
    const ushort xn4[4] = {(ushort)(xnu.x&0xffff),(ushort)(xnu.x>>16),   \
                           (ushort)(xnu.y&0xffff),(ushort)(xnu.y>>16)};  \
    const float bhv[4] = {bh4[dt].x, bh4[dt].y, bh4[dt].z, bh4[dt].w};   \
    union{ ushort u[4]; uint2 v; } p;                                    \
    _Pragma("unroll") for(int r=0;r<4;r++){                              \
      const float hold = dn ? 0.f : hf[dt][r];                           \
      const float rg = sigm(b2f(xr4[r]) + acc[0][dt][r]);                \
      const float zg = sigm(b2f(xz4[r]) + acc[1][dt][r]);                \
      const float ng = tanh_f(b2f(xn4[r]) + rg*(acc[2][dt][r] + bhv[r]));\
      const float hv = (1.f - zg)*ng + zg*hold;                          \
      hf[dt][r] = hv; p.u[r] = f2b(hv); }                                \
    pv[dt] = p.v; } }

__global__ __launch_bounds__(128, 1) void k_scan_coop(
    const ushort* __restrict__ xg,        // scan-native layout, chunk-local
    const void* __restrict__ donep,
    const int* __restrict__ flagp, const float* __restrict__ h_in,
    const ushort* __restrict__ WhT, const float* __restrict__ bhn,
    ushort* __restrict__ ys, float* __restrict__ h_io,
    float* __restrict__ h_last, ushort* __restrict__ hbf,   // [2][8g][16ds][32r][32d]
    int t0, int steps, int* __restrict__ cntbase, int* __restrict__ xcc_tab){
  __shared__ __align__(16) ushort whs[96*512];     // 96 KB (3 gates x 32 d)
  __shared__ __align__(16) ushort xgs[2][3072];    // 12 KB double-buffered xg slice
  __shared__ unsigned char dns[512*32];            // 16 KB done bits for this group
  __shared__ int fastf;
  const int tid = threadIdx.x;
  const int m = tid >> 6, l = tid & 63, l16 = l & 15, l4 = l >> 4;
  const int bid = blockIdx.x;
  const int g = bid & 7, ds = bid >> 3;            // ds in [0,16): 32-d slice
  const int use8 = *flagp;
  const unsigned char* d8 = (const unsigned char*)donep;
  const int* d32 = (const int*)donep;
  int* cntL = cntbase;          // L2-local flags
  int* cntA = cntbase + 256;    // agent-scope flags (mirror / slow path)

  // ---- stage WhT slice into LDS, swizzled: 96 rows (gate*32 + dloc) x 512 ----
  for(int e = tid; e < 6144; e += 128){
    const int lr = e >> 6;              // local row 0..95
    const int kc = (e & 63) << 3;       // k 0..504 step 8
    const int grow_w = (lr >> 5)*DD + ds*32 + (lr & 31);
    short8 v = *(const short8*)(WhT + (size_t)grow_w*DD + kc);
    int boff = ((lr << 10) + (kc << 1)) ^ ((lr & 7) << 4);
    *(short8*)((char*)whs + boff) = v;
  }
  // ---- stage done bits for this group's 32 rows x steps ----
  for(int e = tid; e < steps*32; e += 128){
    const int tloc = e >> 5, r = e & 31;
    const int gi = (t0 + tloc)*BB + g*32 + r;
    dns[e] = use8 ? (d8[gi] != 0) : (d32[gi] != 0);
  }

  // ---- thread ownership: 1 batch row x 8 d (2 tiles of 4 consecutive) ----
  const int r32 = m*16 + l16;           // local row index 0..31
  const int row = g*32 + r32;           // batch row
  float4 bh4[2];
  bh4[0] = *(const float4*)(bhn + ds*32 + l4*4);
  bh4[1] = *(const float4*)(bhn + ds*32 + 16 + l4*4);

  // ---- prologue: load h f32, publish bf16 into hbf[0] (IF-coherent) ----
  float hf[2][4];
  #pragma unroll
  for(int dt=0; dt<2; dt++){
    const float4 hv4 = *(const float4*)(h_in + (size_t)row*DD + ds*32 + dt*16 + l4*4);
    hf[dt][0]=hv4.x; hf[dt][1]=hv4.y; hf[dt][2]=hv4.z; hf[dt][3]=hv4.w;
    union{ ushort u[4]; uint2 v; } p;
    #pragma unroll
    for(int r=0;r<4;r++) p.u[r] = f2b(hf[dt][r]);
    const ushort* pp = hbf + (size_t)(g*16 + ds)*1024 + r32*32 + dt*16 + l4*4;
    asm volatile("global_store_dwordx2 %0, %1, off sc0 sc1" :: "v"(pp), "v"(p.v) : "memory");
  }
  // ---- stage xg slice for step 0 into xgs[0] ----
  XG_PREFETCH(0, 0);
  // ---- publish own XCC id, exchange via the safe agent barrier ----
  int my_xcc;
  asm volatile("s_getreg_b32 %0, hwreg(HW_REG_XCC_ID)" : "=s"(my_xcc));
  if(tid == 0){
    int* p = xcc_tab + bid;
    asm volatile("global_store_dword %0, %1, off sc0 sc1" :: "v"(p), "v"(my_xcc) : "memory");
  }
  bar_slow(cntA, g, ds, 1, tid);
  {
    int bad = 0;
    if(tid < 16){
      const int* p = xcc_tab + tid*8 + g;   // member bid = tid*8 + g
      int v;
      asm volatile("global_load_dword %0, %1, off sc0 sc1" : "=v"(v) : "v"(p) : "memory");
      asm volatile("s_waitcnt vmcnt(0)" ::: "memory");
      bad = (v != my_xcc);
    }
    const int anybad = __any(bad);
    if(tid == 0) fastf = !anybad;
    __syncthreads();
  }
  const int fast = fastf;

  // wh-frag swizzle bases (gate gi, d-tile dt -> local row gi*32 + dt*16 + l16)
  int rb[3][2], sw[3][2];
  #pragma unroll
  for(int gi=0; gi<3; gi++)
    #pragma unroll
    for(int dt=0; dt<2; dt++){
      const int lr = gi*32 + dt*16 + l16;
      rb[gi][dt] = lr << 10;
      sw[gi][dt] = (lr & 7) << 4;
    }
  const ushort* hb0 = hbf;
  const ushort* hb1 = hbf + (size_t)BB*DD;
  // consumer base: k-chunk j lives in region (g*16 + j); within: r32*64B + l4*16B
  const size_t csub = (size_t)r32*32 + l4*8;   // ushorts
  int cur = 0;

  if(fast){
    asm volatile("buffer_inv sc0" ::: "memory");
    for(int tl = 0; tl < steps; tl++){
      const ushort* hcur = (tl & 1) ? hb1 : hb0;
      ushort* hnxt = (ushort*)((tl & 1) ? hb0 : hb1);
      const bool dn = dns[tl*32 + r32];
      const ushort* hgrp = hcur + (size_t)g*16384 + csub;
      DECL_A;
      ALOADS(ALD_F);
      __builtin_amdgcn_sched_barrier(0);
      if(tl + 1 < steps){
        XG_PREFETCH(tl+1, cur^1);
        __builtin_amdgcn_sched_barrier(0);
        asm volatile("s_waitcnt vmcnt(3)" ::: "memory");   // A-loads done, 3 xg in flight
      } else {
        asm volatile("s_waitcnt vmcnt(0)" ::: "memory");
      }
      __builtin_amdgcn_sched_barrier(0);
      if(__builtin_expect(dn, 0)) ZERO_A;
      f32x4 acc[3][2] = {};
      MFMA96;
      uint2 pv[2];
      GRU_EPI;
      const ushort* ppA = hnxt + (size_t)(g*16 + ds)*1024 + r32*32 + l4*4;
      const ushort* ppB = ppA + 16;
      asm volatile("global_store_dwordx2 %0, %1, off" :: "v"(ppA), "v"(pv[0]) : "memory");
      asm volatile("global_store_dwordx2 %0, %1, off" :: "v"(ppB), "v"(pv[1]) : "memory");
      bar_fast(cntL, cntA, g, ds, tl + 2, tid);
      ushort* yb = ys + ((size_t)tl*BB + row)*DD + ds*32 + l4*4;
      *(uint2*)yb = pv[0];
      *(uint2*)(yb + 16) = pv[1];
      cur ^= 1;
    }
  } else {
    for(int tl = 0; tl < steps; tl++){
      const ushort* hcur = (tl & 1) ? hb1 : hb0;
      ushort* hnxt = (ushort*)((tl & 1) ? hb0 : hb1);
      const bool dn = dns[tl*32 + r32];
      const ushort* hgrp = hcur + (size_t)g*16384 + csub;
      DECL_A;
      ALOADS(ALD_S);
      __builtin_amdgcn_sched_barrier(0);
      if(tl + 1 < steps){
        XG_PREFETCH(tl+1, cur^1);
        __builtin_amdgcn_sched_barrier(0);
        asm volatile("s_waitcnt vmcnt(3)" ::: "memory");
      } else {
        asm volatile("s_waitcnt vmcnt(0)" ::: "memory");
      }
      __builtin_amdgcn_sched_barrier(0);
      if(__builtin_expect(dn, 0)) ZERO_A;
      f32x4 acc[3][2] = {};
      MFMA96;
      uint2 pv[2];
      GRU_EPI;
      const ushort* ppA = hnxt + (size_t)(g*16 + ds)*1024 + r32*32 + l4*4;
      const ushort* ppB = ppA + 16;
      asm volatile("global_store_dwordx2 %0, %1, off sc0 sc1" :: "v"(ppA), "v"(pv[0]) : "memory");
      asm volatile("global_store_dwordx2 %0, %1, off sc0 sc1" :: "v"(ppB), "v"(pv[1]) : "memory");
      bar_slow(cntA, g, ds, tl + 2, tid);
      ushort* yb = ys + ((size_t)tl*BB + row)*DD + ds*32 + l4*4;
      *(uint2*)yb = pv[0];
      *(uint2*)(yb + 16) = pv[1];
      cur ^= 1;
    }
  }

  #pragma unroll
  for(int dt=0; dt<2; dt++){
    float4 o; o.x=hf[dt][0]; o.y=hf[dt][1]; o.z=hf[dt][2]; o.w=hf[dt][3];
    *(float4*)(h_io   + (size_t)row*DD + ds*32 + dt*16 + l4*4) = o;
    *(float4*)(h_last + (size_t)row*DD + ds*32 + dt*16 + l4*4) = o;
  }
}

// ---------------- fallback GRU scan (16 blocks; scan-native xg layout) ----------------
__global__ __launch_bounds__(1024) void k_scan(const ushort* __restrict__ xg,
                                               const void* __restrict__ donep,
                                               const int* __restrict__ flagp,
                                               const float* __restrict__ h_in,
                                               const ushort* __restrict__ WhT,
                                               const float* __restrict__ bhn,
                                               ushort* __restrict__ ys,
                                               float* __restrict__ h_io,
                                               float* __restrict__ h_last,
                                               int t0, int steps){
  __shared__ __align__(16) float  h_f[16][DD];
  __shared__ __align__(16) ushort h_b[16][DD];
  const int tid = threadIdx.x;
  const int w = tid >> 6, l = tid & 63, l16 = l & 15, l4 = l >> 4;
  const int b0 = blockIdx.x * 16;
  const int use8 = *flagp;
  const unsigned char* d8 = (const unsigned char*)donep;
  const int* d32 = (const int*)donep;

  for(int e = tid; e < 16*DD; e += 1024){
    int b = e >> 9, dd = e & (DD-1);
    float v = h_in[(size_t)(b0 + b)*DD + dd];
    h_f[b][dd] = v; h_b[b][dd] = f2b(v);
  }
  __syncthreads();

  const int dbase = w * 32;
  const ushort* bp[6];
  #pragma unroll
  for(int g=0; g<3; g++)
    #pragma unroll
    for(int nt=0; nt<2; nt++)
      bp[g*2+nt] = WhT + (size_t)(g*DD + dbase + nt*16 + l16) * DD;

  for(int tl = 0; tl < steps; tl++){
    const int drow = (t0 + tl)*BB + b0;
    const bool dnA = use8 ? (d8[drow + l16] != 0) : (d32[drow + l16] != 0);
    f32x4 acc[3][2] = {};
    const short8 zf = {0,0,0,0,0,0,0,0};
    for(int k0 = 0; k0 < DD; k0 += 32){
      const int kb = k0 + l4*8;
      short8 a = *(const short8*)&h_b[l16][kb];
      if(dnA) a = zf;
      #pragma unroll
      for(int g=0; g<3; g++)
        #pragma unroll
        for(int nt=0; nt<2; nt++){
          const short8 b = *(const short8*)(bp[g*2+nt] + kb);
          acc[g][nt] = __builtin_amdgcn_mfma_f32_16x16x32_bf16(a, b, acc[g][nt], 0, 0, 0);
        }
    }
    float hnew[2][4];
    #pragma unroll
    for(int nt=0; nt<2; nt++){
      const int dd = dbase + nt*16 + l16;
      const float bh = bhn[dd];
      const int dsp = dd >> 5, c32 = dd & 31;
      #pragma unroll
      for(int r=0; r<4; r++){
        const int brow = l4*4 + r;
        const int grow = b0 + brow;
        const int gg = grow >> 5, r32 = grow & 31;
        const bool dn = use8 ? (d8[drow + brow] != 0) : (d32[drow + brow] != 0);
        const size_t sbase = ((((size_t)tl*16 + dsp)*8 + gg)*3)*1024 + r32*32 + c32;
        const float xr = b2f(xg[sbase]);
        const float xz = b2f(xg[sbase + 1024]);
        const float xn = b2f(xg[sbase + 2048]);
        const float hold = dn ? 0.f : h_f[brow][dd];
        const float rg = sigm(xr + acc[0][nt][r]);
        const float zg = sigm(xz + acc[1][nt][r]);
        const float ng = tanh_f(xn + rg*(acc[2][nt][r] + bh));
        hnew[nt][r] = (1.f - zg)*ng + zg*hold;
      }
    }
    __syncthreads();
    #pragma unroll
    for(int nt=0; nt<2; nt++){
      const int dd = dbase + nt*16 + l16;
      #pragma unroll
      for(int r=0; r<4; r++){
        const int brow = l4*4 + r;
        const size_t rowl = (size_t)(tl*BB + b0 + brow);
        const float hv = hnew[nt][r];
        h_f[brow][dd] = hv;
        h_b[brow][dd] = f2b(hv);
        ys[rowl*DD + dd] = f2b(hv);
      }
    }
    __syncthreads();
  }

  for(int e = tid; e < 16*DD; e += 1024){
    int b = e >> 9, dd = e & (DD-1);
    float v = h_f[b][dd];
    h_io[(size_t)(b0 + b)*DD + dd] = v;
    h_last[(size_t)(b0 + b)*DD + dd] = v;
  }
}

// ---------------- value GEMV ----------------
__global__ __launch_bounds__(256) void k_value(const ushort* __restrict__ critic,
                                               const float* __restrict__ W2,
                                               const float* __restrict__ b2,
                                               float* __restrict__ val){
  const int w = threadIdx.x >> 6, l = threadIdx.x & 63;
  const size_t row = (size_t)blockIdx.x*4 + w;
  const ushort* cp = critic + row*HH + l*8;
  const float* wp = W2 + l*8;
  float s = 0.f;
  #pragma unroll
  for(int j=0;j<8;j++) s += b2f(cp[j]) * wp[j];
  for(int off=32; off; off>>=1) s += __shfl_down(s, off, 64);
  if(l == 0) val[row] = s + b2[0];
}

extern "C" void kernel_launch(void* const* d_in, const int* in_sizes, int n_in,
                              void* d_out, int out_size, void* d_ws, size_t ws_size,
                              hipStream_t stream){
  const float* obs    = (const float*)d_in[0];
  const void*  done   = d_in[1];
  const float* hstate = (const float*)d_in[2];
  const float* W_emb  = (const float*)d_in[3];
  const float* b_emb  = (const float*)d_in[4];
  const float* Wi     = (const float*)d_in[5];
  const float* bi     = (const float*)d_in[6];
  const float* Wh     = (const float*)d_in[7];
  const float* bhn    = (const float*)d_in[8];
  const float* W1     = (const float*)d_in[9];
  const float* b1     = (const float*)d_in[10];
  const float* W2     = (const float*)d_in[11];
  const float* b2     = (const float*)d_in[12];
  float* out = (float*)d_out;
  char*  ws  = (char*)d_ws;

  // ---- fixed ws region ----
  ushort* WembT = (ushort*)(ws + 0);           // 262144
  ushort* WiT   = (ushort*)(ws + 262144);      // -> 1835008
  ushort* WhT   = (ushort*)(ws + 1835008);     // -> 3407872
  ushort* W1T   = (ushort*)(ws + 3407872);     // -> 3932160
  int*    flag  = (int*)   (ws + 3932160);     // 4
  float*  hio   = (float*) (ws + 3936256);     // -> 4460544
  ushort* hbf   = (ushort*)(ws + 4460544);     // 2*256*512*2 = 524288 -> 4984832
  int*    cnt   = (int*)   (ws + 4984832);     // cntL[256] + cntA[256] = 2KB
  int*    xcc   = (int*)   (ws + 5017600);     // 128 ints
  const size_t FIX = 5242880;                  // 5 MiB

  int TC = 0;
  {
    const int cands[6] = {512, 256, 128, 64, 32, 16};
    for(int i = 0; i < 6; i++){
      size_t need = FIX + (size_t)cands[i] * 1310720u;
      if(need <= ws_size){ TC = cands[i]; break; }
    }
  }
  if(TC == 0) return;

  ushort* emb_c  = (ushort*)(ws + FIX);
  ushort* xg_c   = (ushort*)(ws + FIX + (size_t)TC*262144u);
  ushort* ys_c   = (ushort*)(ws + FIX + (size_t)TC*1048576u);
  ushort* crit_c = emb_c;
  ushort* obs_bf = ys_c;   // obs_bf overlaps ys: dead before scan

  k_transpose_bf16<<<(OBSD*DD+255)/256, 256, 0, stream>>>(W_emb, WembT, OBSD, DD);
  k_transpose_bf16<<<(DD*3*DD+255)/256, 256, 0, stream>>>(Wi, WiT, DD, 3*DD);
  k_transpose_bf16<<<(DD*3*DD+255)/256, 256, 0, stream>>>(Wh, WhT, DD, 3*DD);
  k_transpose_bf16<<<(DD*HH+255)/256, 256, 0, stream>>>(W1, W1T, DD, HH);
  k_detect<<<1, 256, 0, stream>>>((const int*)done, flag);

  const int nchunks = TT / TC;
  for(int c = 0; c < nchunks; c++){
    const int Mc = TC * BB;
    const size_t row0 = (size_t)c * Mc;
    k_f32_to_bf16<<<(Mc*OBSD/4 + 255)/256, 256, 0, stream>>>(obs + row0*OBSD, obs_bf,
                                                             Mc*OBSD/4);
    k_gemm128<<<dim3(Mc/128, DD/128), 256, 0, stream>>>(obs_bf, WembT, b_emb,
                                                        emb_c, Mc, DD, OBSD, 1, 0);
    k_gemm128<<<dim3(Mc/128, (3*DD)/128), 256, 0, stream>>>(emb_c, WiT, bi,
                                                            xg_c, Mc, 3*DD, DD, 0, 1);
    {
      const ushort* xg_a = xg_c;  const void* done_a = done;
      const int* flag_a = flag;   const float* hin_a = (c == 0) ? hstate : hio;
      const ushort* wht_a = WhT;  const float* bhn_a = bhn;
      ushort* ys_a = ys_c;        float* hio_a = hio;
      float* hl_a = out;          ushort* hbf_a = hbf;
      int t0_a = c*TC;            int steps_a = TC;
      int* cnt_a = cnt;           int* xcc_a = xcc;
      void* args[14] = { (void*)&xg_a, (void*)&done_a, (void*)&flag_a, (void*)&hin_a,
                         (void*)&wht_a, (void*)&bhn_a, (void*)&ys_a, (void*)&hio_a,
                         (void*)&hl_a, (void*)&hbf_a, (void*)&t0_a, (void*)&steps_a,
                         (void*)&cnt_a, (void*)&xcc_a };
      hipMemsetAsync(cnt, 0, 4096, stream);
      hipError_t err = hipLaunchCooperativeKernel((const void*)k_scan_coop,
                                                  dim3(128), dim3(128), args, 0, stream);
      if(err != hipSuccess){
        k_scan<<<16, 1024, 0, stream>>>(xg_c, done, flag, hin_a, WhT, bhn,
                                        ys_c, hio, out, c*TC, TC);
      }
    }
    k_gemm128<<<dim3(Mc/128, HH/128), 256, 0, stream>>>(ys_c, W1T, b1,
                                                        crit_c, Mc, HH, DD, 1, 0);
    k_value<<<Mc/4, 256, 0, stream>>>(crit_c, W2, b2, out + (size_t)BB*DD + row0);
  }
}

// Round 13
// 3117.275 us; speedup vs baseline: 7.3913x; 7.3913x over previous
//
#include <hip/hip_runtime.h>

// Problem dims
#define TT   512
#define BB   256
#define OBSD 256
#define DD   512
#define HH   512
#define MROWS (TT*BB)   // 131072

typedef __attribute__((ext_vector_type(8))) short short8;
typedef __attribute__((ext_vector_type(4))) float f32x4;

__device__ __forceinline__ ushort f2b(float f){
  unsigned int x = __float_as_uint(f);
  x = (x + 0x7fffu + ((x >> 16) & 1u)) >> 16;   // RNE
  return (ushort)x;
}
__device__ __forceinline__ float b2f(ushort u){
  return __uint_as_float(((unsigned int)u) << 16);
}
__device__ __forceinline__ float sigm(float x){ return 1.f/(1.f + __expf(-x)); }
__device__ __forceinline__ float tanh_f(float x){ return 1.f - 2.f/(__expf(2.f*x) + 1.f); }

// ---------------- transpose f32 [K,N] -> bf16 [N,K] ----------------
__global__ void k_transpose_bf16(const float* __restrict__ W, ushort* __restrict__ Wt,
                                 int K, int N){
  int i = blockIdx.x*256 + threadIdx.x;
  if(i >= K*N) return;
  int k = i / N, n = i % N;
  Wt[(size_t)n*K + k] = f2b(W[i]);
}

// ---------------- f32 -> bf16 elementwise (vectorized) ----------------
__global__ void k_f32_to_bf16(const float* __restrict__ in, ushort* __restrict__ out,
                              int n4){
  int i = blockIdx.x*256 + threadIdx.x;
  if(i >= n4) return;
  const float4 v = ((const float4*)in)[i];
  union{ ushort u[4]; uint2 d; } p;
  p.u[0] = f2b(v.x); p.u[1] = f2b(v.y); p.u[2] = f2b(v.z); p.u[3] = f2b(v.w);
  ((uint2*)out)[i] = p.d;
}

// ---------------- detect done dtype (byte-packed vs 4-byte) ----------------
__global__ void k_detect(const int* __restrict__ done, int* __restrict__ flag){
  __shared__ int cnt;
  if(threadIdx.x == 0) cnt = 0;
  __syncthreads();
  int c = 0;
  for(int i = threadIdx.x; i < 32768; i += 256) c += (done[i] != 0);
  for(int off = 32; off; off >>= 1) c += __shfl_down(c, off, 64);
  if((threadIdx.x & 63) == 0) atomicAdd(&cnt, c);
  __syncthreads();
  if(threadIdx.x == 0) *flag = (cnt > 700) ? 1 : 0;  // 1 => byte-packed bools
}

// ---------------- 128x128-tile MFMA GEMM, 2-phase double-buffered staging ----------------
#define GSTAGE(buf, k0v) { \
  _Pragma("unroll") \
  for(int j = 0; j < 2; j++){ \
    const int flat = tid*16 + j*4096;        /* byte offset in 8KB tile */ \
    const int rw  = flat >> 6;               /* 64B per row */ \
    const int ke  = (flat & 63) >> 1;        /* k-elem within 32 */ \
    __builtin_amdgcn_global_load_lds( \
      (const __attribute__((address_space(1))) void*)(A + (m0+rw)*(size_t)K + (k0v) + ke), \
      (__attribute__((address_space(3))) void*)((char*)As[buf] + flat), 16, 0, 0); \
    __builtin_amdgcn_global_load_lds( \
      (const __attribute__((address_space(1))) void*)(Bt + (n0+rw)*(size_t)K + (k0v) + ke), \
      (__attribute__((address_space(3))) void*)((char*)Bs[buf] + flat), 16, 0, 0); \
  } }
#define GCOMPUTE(buf) { \
    short8 af[4], bf[4]; \
    _Pragma("unroll") for(int mi=0;mi<4;mi++) \
      af[mi] = *(const short8*)((const char*)As[buf] + (wr*64+mi*16+l16)*64 + l4*16); \
    _Pragma("unroll") for(int ni=0;ni<4;ni++) \
      bf[ni] = *(const short8*)((const char*)Bs[buf] + (wc*64+ni*16+l16)*64 + l4*16); \
    _Pragma("unroll") for(int mi=0;mi<4;mi++) \
      _Pragma("unroll") for(int ni=0;ni<4;ni++) \
        acc[mi][ni] = __builtin_amdgcn_mfma_f32_16x16x32_bf16(af[mi], bf[ni], acc[mi][ni], 0,0,0); }

__global__ __launch_bounds__(256) void k_gemm128(const ushort* __restrict__ A,
                                                 const ushort* __restrict__ Bt,
                                                 const float* __restrict__ bias,
                                                 ushort* __restrict__ C,
                                                 int M, int N, int K, int relu,
                                                 int xg_layout){
  __shared__ __align__(16) ushort As[2][4096];   // 2 x 8KB
  __shared__ __align__(16) ushort Bs[2][4096];
  const int tid = threadIdx.x;
  const int l = tid & 63, l16 = l & 15, l4 = l >> 4;
  const int w = tid >> 6, wr = w >> 1, wc = w & 1;
  const size_t m0 = (size_t)blockIdx.x*128, n0 = (size_t)blockIdx.y*128;
  f32x4 acc[4][4] = {};

  GSTAGE(0, 0);
  asm volatile("s_waitcnt vmcnt(0)" ::: "memory");
  __syncthreads();
  int cur = 0;
  for(int k0 = 32; k0 < K; k0 += 32){
    GSTAGE(cur^1, k0);           // prefetch next tile while computing current
    GCOMPUTE(cur);
    asm volatile("s_waitcnt vmcnt(0)" ::: "memory");
    __syncthreads();
    cur ^= 1;
  }
  GCOMPUTE(cur);

  #pragma unroll
  for(int ni=0;ni<4;ni++){
    const int col = (int)n0 + wc*64 + ni*16 + l16;
    const float bv = bias[col];
    #pragma unroll
    for(int mi=0;mi<4;mi++){
      #pragma unroll
      for(int r=0;r<4;r++){
        const int row = (int)m0 + wr*64 + mi*16 + l4*4 + r;
        float v = acc[mi][ni][r] + bv;
        if(relu) v = fmaxf(v, 0.f);
        size_t addr;
        if(xg_layout){
          const int tl = row >> 8, brow = row & 255;
          const int gg = brow >> 5, r32 = brow & 31;
          const int gate = col >> 9, cw = col & 511, ds2 = cw >> 4, c16 = cw & 15;
          addr = ((((size_t)tl*32 + ds2)*8 + gg)*3 + gate)*512 + r32*16 + c16;
        } else {
          addr = (size_t)row*N + col;
        }
        C[addr] = f2b(v);
      }
    }
  }
}

// ======================= cooperative GRU scan =======================
// 256 blocks x 128 thr (2 waves). Group g = bid&7, ds = bid>>3 (same-XCD fast path,
// r9-proven; r11 counted-vmcnt xg prefetch). r13: fast-barrier poll uses plain
// loads (buffer_inv + 1 L2 line read/iter) instead of 32 same-line atomic RMWs —
// removes TCC RMW serialization that also delayed the arrival store. Arrival =
// plain write-through store + agent-scope mirror (deadlock safety net kept).
__device__ __forceinline__ void bar_slow(int* cntA, int g, int ds, int target, int tid){
  asm volatile("s_waitcnt vmcnt(0)" ::: "memory");
  __syncthreads();
  if(tid == 0)
    __hip_atomic_store(cntA + g*32 + ds, target,
                       __ATOMIC_RELAXED, __HIP_MEMORY_SCOPE_AGENT);
  if(tid < 32){
    const int* fp = cntA + g*32 + tid;
    while(__hip_atomic_load(fp, __ATOMIC_RELAXED, __HIP_MEMORY_SCOPE_AGENT) < target)
      __builtin_amdgcn_s_sleep(1);
  }
  __syncthreads();
}

__device__ __forceinline__ void bar_fast(int* cntL, int* cntA, int g, int ds,
                                         int target, int tid){
  asm volatile("s_waitcnt vmcnt(0)" ::: "memory");   // h stores landed in local L2
  __syncthreads();
  if(tid == 0){
    int* pL = cntL + g*32 + ds;
    asm volatile("global_store_dword %0, %1, off" :: "v"(pL), "v"(target) : "memory");
    __hip_atomic_store(cntA + g*32 + ds, target,
                       __ATOMIC_RELAXED, __HIP_MEMORY_SCOPE_AGENT);   // mirror
  }
  if(tid < 32){
    const int* fpL = cntL + g*32 + tid;
    const int* fpA = cntA + g*32 + tid;
    int it = 0;
    for(;;){
      asm volatile("buffer_inv sc0" ::: "memory");    // drop stale L1 copy
      int v;
      asm volatile("global_load_dword %0, %1, off" : "=v"(v) : "v"(fpL) : "memory");
      asm volatile("s_waitcnt vmcnt(0)" ::: "memory");
      if(v >= target) break;
      if((++it & 15) == 0 &&
         __hip_atomic_load(fpA, __ATOMIC_RELAXED, __HIP_MEMORY_SCOPE_AGENT) >= target)
        break;                                        // safety net: agent mirror
      __builtin_amdgcn_s_sleep(1);
    }
  }
  __syncthreads();
  asm volatile("buffer_inv sc0" ::: "memory");        // L1 invalidate before peer-h reads
}

#define ALD_S(v, j) { const ushort* pj_ = hgrp + (j)*1024; \
  asm volatile("global_load_dwordx4 %0, %1, off sc0 sc1" : "=&v"(v) : "v"(pj_)); }
#define ALD_F(v, j) { const ushort* pj_ = hgrp + (j)*1024; \
  asm volatile("global_load_dwordx4 %0, %1, off" : "=&v"(v) : "v"(pj_)); }
#define DECL_A short8 a0,a1,a2,a3,a4,a5,a6,a7,a8,a9,a10,a11,a12,a13,a14,a15
#define ALOADS(M) M(a0,0);M(a1,1);M(a2,2);M(a3,3);M(a4,4);M(a5,5);M(a6,6);M(a7,7); \
  M(a8,8);M(a9,9);M(a10,10);M(a11,11);M(a12,12);M(a13,13);M(a14,14);M(a15,15)
#define ZERO_A { const short8 z = {0,0,0,0,0,0,0,0}; \
  a0=z;a1=z;a2=z;a3=z;a4=z;a5=z;a6=z;a7=z;a8=z;a9=z;a10=z;a11=z;a12=z;a13=z;a14=z;a15=z; }
#define STEPK(ak, k0lit) { const int kboff = ((k0lit + l4*8) << 1); \
  _Pragma("unroll") for(int gi=0; gi<3; gi++){ \
    const short8 wf = *(const short8*)((const char*)whs + ((rb[gi] + kboff) ^ sw[gi])); \
    acc[gi] = __builtin_amdgcn_mfma_f32_16x16x32_bf16(wf, ak, acc[gi], 0, 0, 0); } }
#define MFMA48 STEPK(a0,0) STEPK(a1,32) STEPK(a2,64) STEPK(a3,96) STEPK(a4,128) \
  STEPK(a5,160) STEPK(a6,192) STEPK(a7,224) STEPK(a8,256) STEPK(a9,288) STEPK(a10,320) \
  STEPK(a11,352) STEPK(a12,384) STEPK(a13,416) STEPK(a14,448) STEPK(a15,480)
// 2 global_load_lds per wave (uniform count). Block = 2 waves (m in {0,1}).
// Wave 0: regions 0 and 2; wave 1: regions 1 and 2 (dup of 2 is identical bytes).
#define XG_PREFETCH(tls, nb) { \
  const ushort* slb_ = xg + (((size_t)(tls)*32 + ds)*8 + g)*1536; \
  const int q0_ = m ? 512 : 0; \
  __builtin_amdgcn_global_load_lds( \
    (const __attribute__((address_space(1))) void*)(slb_ + q0_ + l*8), \
    (__attribute__((address_space(3))) void*)(&xgs[nb][q0_]), 16, 0, 0); \
  __builtin_amdgcn_global_load_lds( \
    (const __attribute__((address_space(1))) void*)(slb_ + 1024 + l*8), \
    (__attribute__((address_space(3))) void*)(&xgs[nb][1024]), 16, 0, 0); }
#define GRU_EPI(pv) { \
  const uint2 xru = *(const uint2*)&xgs[cur][        r32*16 + l4*4]; \
  const uint2 xzu = *(const uint2*)&xgs[cur][ 512 +  r32*16 + l4*4]; \
  const uint2 xnu = *(const uint2*)&xgs[cur][1024 +  r32*16 + l4*4]; \
  const ushort xr4[4] = {(ushort)(xru.x&0xffff),(ushort)(xru.x>>16), \
                         (ushort)(xru.y&0xffff),(ushort)(xru.y>>16)}; \
  const ushort xz4[4] = {(ushort)(xzu.x&0xffff),(ushort)(xzu.x>>16), \
                         (ushort)(xzu.y&0xffff),(ushort)(xzu.y>>16)}; \
  const ushort xn4[4] = {(ushort)(xnu.x&0xffff),(ushort)(xnu.x>>16), \
                         (ushort)(xnu.y&0xffff),(ushort)(xnu.y>>16)}; \
  const float bhv[4] = {bh4.x, bh4.y, bh4.z, bh4.w}; \
  union{ ushort u[4]; uint2 v; } p; \
  _Pragma("unroll") for(int r=0;r<4;r++){ \
    const float hold = dn ? 0.f : hf[r]; \
    const float rg = sigm(b2f(xr4[r]) + acc[0][r]); \
    const float zg = sigm(b2f(xz4[r]) + acc[1][r]); \
    const float ng = tanh_f(b2f(xn4[r]) + rg*(acc[2][r] + bhv[r])); \
    const float hv = (1.f - zg)*ng + zg*hold; \
    hf[r] = hv; p.u[r] = f2b(hv); } \
  pv = p.v; }

__global__ __launch_bounds__(128, 1) void k_scan_coop(
    const ushort* __restrict__ xg,        // scan-native layout, chunk-local
    const void* __restrict__ donep,
    const int* __restrict__ flagp, const float* __restrict__ h_in,
    const ushort* __restrict__ WhT, const float* __restrict__ bhn,
    ushort* __restrict__ ys, float* __restrict__ h_io,
    float* __restrict__ h_last, ushort* __restrict__ hbf,   // [2][8g][32ds][32r][16d]
    int t0, int steps, int* __restrict__ cntbase, int* __restrict__ xcc_tab){
  __shared__ __align__(16) ushort whs[48*512];     // 48 KB
  __shared__ __align__(16) ushort xgs[2][1536];    // 6 KB double-buffered xg slice
  __shared__ unsigned char dns[512*32];            // 16 KB done bits for this group
  __shared__ int fastf;
  const int tid = threadIdx.x;
  const int m = tid >> 6, l = tid & 63, l16 = l & 15, l4 = l >> 4;
  const int bid = blockIdx.x;
  const int g = bid & 7, ds = bid >> 3;            // XCD-friendly grouping
  const int use8 = *flagp;
  const unsigned char* d8 = (const unsigned char*)donep;
  const int* d32 = (const int*)donep;
  int* cntL = cntbase;          // 256 ints: L2-local flags
  int* cntA = cntbase + 256;    // 256 ints: agent-scope flags (mirror / slow path)

  // ---- stage WhT slice into LDS, swizzled ----
  for(int e = tid; e < 3072; e += 128){
    const int lr = e >> 6;              // local row 0..47 (gate*16 + d-within-16)
    const int kc = (e & 63) << 3;       // k 0..504 step 8
    const int grow_w = (lr >> 4)*DD + ds*16 + (lr & 15);
    short8 v = *(const short8*)(WhT + (size_t)grow_w*DD + kc);
    int boff = ((lr << 10) + (kc << 1)) ^ ((lr & 7) << 4);
    *(short8*)((char*)whs + boff) = v;
  }
  // ---- stage done bits for this group's 32 rows x steps ----
  for(int e = tid; e < steps*32; e += 128){
    const int tloc = e >> 5, r = e & 31;
    const int gi = (t0 + tloc)*BB + g*32 + r;
    dns[e] = use8 ? (d8[gi] != 0) : (d32[gi] != 0);
  }

  // ---- thread ownership: 1 batch row x 4 consecutive d ----
  const int r32 = m*16 + l16;           // local row index 0..31
  const int row = g*32 + r32;           // batch row
  const int d0  = ds*16 + l4*4;         // first of 4 d outputs
  const float4 bh4 = *(const float4*)(bhn + d0);

  // ---- prologue: load h f32, publish bf16 into hbf[0] (IF-coherent, safe pre-detect) ----
  float hf[4];
  {
    const float4 hv4 = *(const float4*)(h_in + (size_t)row*DD + d0);
    hf[0]=hv4.x; hf[1]=hv4.y; hf[2]=hv4.z; hf[3]=hv4.w;
    union{ ushort u[4]; uint2 v; } p;
    #pragma unroll
    for(int r=0;r<4;r++) p.u[r] = f2b(hf[r]);
    const ushort* pp = hbf + (size_t)g*16384 + ds*512 + r32*16 + l4*4;
    asm volatile("global_store_dwordx2 %0, %1, off sc0 sc1" :: "v"(pp), "v"(p.v) : "memory");
  }
  // ---- stage xg slice for step 0 into xgs[0] ----
  XG_PREFETCH(0, 0);
  // ---- publish own XCC id, exchange via the safe agent barrier ----
  int my_xcc;
  asm volatile("s_getreg_b32 %0, hwreg(HW_REG_XCC_ID)" : "=s"(my_xcc));
  if(tid == 0){
    int* p = xcc_tab + bid;
    asm volatile("global_store_dword %0, %1, off sc0 sc1" :: "v"(p), "v"(my_xcc) : "memory");
  }
  bar_slow(cntA, g, ds, 1, tid);
  {
    int bad = 0;
    if(tid < 32){
      const int* p = xcc_tab + tid*8 + g;   // member bid = tid*8 + g
      int v;
      asm volatile("global_load_dword %0, %1, off sc0 sc1" : "=v"(v) : "v"(p) : "memory");
      asm volatile("s_waitcnt vmcnt(0)" ::: "memory");
      bad = (v != my_xcc);
    }
    const int anybad = __any(bad);
    if(tid == 0) fastf = !anybad;
    __syncthreads();
  }
  const int fast = fastf;

  // wh-frag swizzle bases (gate gi -> local row gi*16 + l16)
  int rb[3], sw[3];
  #pragma unroll
  for(int gi=0; gi<3; gi++){
    const int lr = gi*16 + l16;
    rb[gi] = lr << 10;
    sw[gi] = (lr & 7) << 4;
  }
  const ushort* hb0 = hbf;
  const ushort* hb1 = hbf + (size_t)BB*DD;
  // consumer base within group region: chunk (l4>>1), within-chunk elem (l4&1)*8
  const size_t csub = (size_t)((l4>>1) << 9) + (size_t)r32*16 + ((l4&1) << 3);
  int cur = 0;

  if(fast){
    asm volatile("buffer_inv sc0" ::: "memory");   // pre-loop L1 inv (prologue h via IF)
    for(int tl = 0; tl < steps; tl++){
      const ushort* hcur = (tl & 1) ? hb1 : hb0;
      ushort* hnxt = (ushort*)((tl & 1) ? hb0 : hb1);
      const bool dn = dns[tl*32 + r32];
      const ushort* hgrp = hcur + (size_t)g*16384 + csub;
      DECL_A;
      ALOADS(ALD_F);
      __builtin_amdgcn_sched_barrier(0);
      if(tl + 1 < steps){
        XG_PREFETCH(tl+1, cur^1);               // issued AFTER A-loads
        __builtin_amdgcn_sched_barrier(0);
        asm volatile("s_waitcnt vmcnt(2)" ::: "memory");   // A-loads done, 2 xg in flight
      } else {
        asm volatile("s_waitcnt vmcnt(0)" ::: "memory");
      }
      __builtin_amdgcn_sched_barrier(0);
      if(__builtin_expect(dn, 0)) ZERO_A;
      f32x4 acc[3] = {};
      MFMA48;
      uint2 pv;
      GRU_EPI(pv);
      const ushort* pp = hnxt + (size_t)g*16384 + ds*512 + r32*16 + l4*4;
      asm volatile("global_store_dwordx2 %0, %1, off" :: "v"(pp), "v"(pv) : "memory");
      bar_fast(cntL, cntA, g, ds, tl + 2, tid);  // vmcnt(0): xg landed during MFMA
      *(uint2*)(ys + ((size_t)tl*BB + row)*DD + d0) = pv;
      cur ^= 1;
    }
  } else {
    for(int tl = 0; tl < steps; tl++){
      const ushort* hcur = (tl & 1) ? hb1 : hb0;
      ushort* hnxt = (ushort*)((tl & 1) ? hb0 : hb1);
      const bool dn = dns[tl*32 + r32];
      const ushort* hgrp = hcur + (size_t)g*16384 + csub;
      DECL_A;
      ALOADS(ALD_S);
      __builtin_amdgcn_sched_barrier(0);
      if(tl + 1 < steps){
        XG_PREFETCH(tl+1, cur^1);
        __builtin_amdgcn_sched_barrier(0);
        asm volatile("s_waitcnt vmcnt(2)" ::: "memory");
      } else {
        asm volatile("s_waitcnt vmcnt(0)" ::: "memory");
      }
      __builtin_amdgcn_sched_barrier(0);
      if(__builtin_expect(dn, 0)) ZERO_A;
      f32x4 acc[3] = {};
      MFMA48;
      uint2 pv;
      GRU_EPI(pv);
      const ushort* pp = hnxt + (size_t)g*16384 + ds*512 + r32*16 + l4*4;
      asm volatile("global_store_dwordx2 %0, %1, off sc0 sc1" :: "v"(pp), "v"(pv) : "memory");
      bar_slow(cntA, g, ds, tl + 2, tid);
      *(uint2*)(ys + ((size_t)tl*BB + row)*DD + d0) = pv;
      cur ^= 1;
    }
  }

  {
    float4 o; o.x=hf[0]; o.y=hf[1]; o.z=hf[2]; o.w=hf[3];
    *(float4*)(h_io   + (size_t)row*DD + d0) = o;
    *(float4*)(h_last + (size_t)row*DD + d0) = o;
  }
}

// ---------------- fallback GRU scan (16 blocks; scan-native xg layout) ----------------
__global__ __launch_bounds__(1024) void k_scan(const ushort* __restrict__ xg,
                                               const void* __restrict__ donep,
                                               const int* __restrict__ flagp,
                                               const float* __restrict__ h_in,
                                               const ushort* __restrict__ WhT,
                                               const float* __restrict__ bhn,
                                               ushort* __restrict__ ys,
                                               float* __restrict__ h_io,
                                               float* __restrict__ h_last,
                                               int t0, int steps){
  __shared__ __align__(16) float  h_f[16][DD];
  __shared__ __align__(16) ushort h_b[16][DD];
  const int tid = threadIdx.x;
  const int w = tid >> 6, l = tid & 63, l16 = l & 15, l4 = l >> 4;
  const int b0 = blockIdx.x * 16;
  const int use8 = *flagp;
  const unsigned char* d8 = (const unsigned char*)donep;
  const int* d32 = (const int*)donep;

  for(int e = tid; e < 16*DD; e += 1024){
    int b = e >> 9, dd = e & (DD-1);
    float v = h_in[(size_t)(b0 + b)*DD + dd];
    h_f[b][dd] = v; h_b[b][dd] = f2b(v);
  }
  __syncthreads();

  const int dbase = w * 32;
  const ushort* bp[6];
  #pragma unroll
  for(int g=0; g<3; g++)
    #pragma unroll
    for(int nt=0; nt<2; nt++)
      bp[g*2+nt] = WhT + (size_t)(g*DD + dbase + nt*16 + l16) * DD;

  for(int tl = 0; tl < steps; tl++){
    const int drow = (t0 + tl)*BB + b0;
    const bool dnA = use8 ? (d8[drow + l16] != 0) : (d32[drow + l16] != 0);
    f32x4 acc[3][2] = {};
    const short8 zf = {0,0,0,0,0,0,0,0};
    for(int k0 = 0; k0 < DD; k0 += 32){
      const int kb = k0 + l4*8;
      short8 a = *(const short8*)&h_b[l16][kb];
      if(dnA) a = zf;
      #pragma unroll
      for(int g=0; g<3; g++)
        #pragma unroll
        for(int nt=0; nt<2; nt++){
          const short8 b = *(const short8*)(bp[g*2+nt] + kb);
          acc[g][nt] = __builtin_amdgcn_mfma_f32_16x16x32_bf16(a, b, acc[g][nt], 0, 0, 0);
        }
    }
    float hnew[2][4];
    #pragma unroll
    for(int nt=0; nt<2; nt++){
      const int dd = dbase + nt*16 + l16;
      const float bh = bhn[dd];
      const int ds2 = dd >> 4, c16 = dd & 15;
      #pragma unroll
      for(int r=0; r<4; r++){
        const int brow = l4*4 + r;
        const int grow = b0 + brow;
        const int gg = grow >> 5, r32 = grow & 31;
        const bool dn = use8 ? (d8[drow + brow] != 0) : (d32[drow + brow] != 0);
        const size_t sbase = (((size_t)tl*32 + ds2)*8 + gg)*1536 + r32*16 + c16;
        const float xr = b2f(xg[sbase]);
        const float xz = b2f(xg[sbase + 512]);
        const float xn = b2f(xg[sbase + 1024]);
        const float hold = dn ? 0.f : h_f[brow][dd];
        const float rg = sigm(xr + acc[0][nt][r]);
        const float zg = sigm(xz + acc[1][nt][r]);
        const float ng = tanh_f(xn + rg*(acc[2][nt][r] + bh));
        hnew[nt][r] = (1.f - zg)*ng + zg*hold;
      }
    }
    __syncthreads();
    #pragma unroll
    for(int nt=0; nt<2; nt++){
      const int dd = dbase + nt*16 + l16;
      #pragma unroll
      for(int r=0; r<4; r++){
        const int brow = l4*4 + r;
        const size_t rowl = (size_t)(tl*BB + b0 + brow);
        const float hv = hnew[nt][r];
        h_f[brow][dd] = hv;
        h_b[brow][dd] = f2b(hv);
        ys[rowl*DD + dd] = f2b(hv);
      }
    }
    __syncthreads();
  }

  for(int e = tid; e < 16*DD; e += 1024){
    int b = e >> 9, dd = e & (DD-1);
    float v = h_f[b][dd];
    h_io[(size_t)(b0 + b)*DD + dd] = v;
    h_last[(size_t)(b0 + b)*DD + dd] = v;
  }
}

// ---------------- value GEMV ----------------
__global__ __launch_bounds__(256) void k_value(const ushort* __restrict__ critic,
                                               const float* __restrict__ W2,
                                               const float* __restrict__ b2,
                                               float* __restrict__ val){
  const int w = threadIdx.x >> 6, l = threadIdx.x & 63;
  const size_t row = (size_t)blockIdx.x*4 + w;
  const ushort* cp = critic + row*HH + l*8;
  const float* wp = W2 + l*8;
  float s = 0.f;
  #pragma unroll
  for(int j=0;j<8;j++) s += b2f(cp[j]) * wp[j];
  for(int off=32; off; off>>=1) s += __shfl_down(s, off, 64);
  if(l == 0) val[row] = s + b2[0];
}

extern "C" void kernel_launch(void* const* d_in, const int* in_sizes, int n_in,
                              void* d_out, int out_size, void* d_ws, size_t ws_size,
                              hipStream_t stream){
  const float* obs    = (const float*)d_in[0];
  const void*  done   = d_in[1];
  const float* hstate = (const float*)d_in[2];
  const float* W_emb  = (const float*)d_in[3];
  const float* b_emb  = (const float*)d_in[4];
  const float* Wi     = (const float*)d_in[5];
  const float* bi     = (const float*)d_in[6];
  const float* Wh     = (const float*)d_in[7];
  const float* bhn    = (const float*)d_in[8];
  const float* W1     = (const float*)d_in[9];
  const float* b1     = (const float*)d_in[10];
  const float* W2     = (const float*)d_in[11];
  const float* b2     = (const float*)d_in[12];
  float* out = (float*)d_out;
  char*  ws  = (char*)d_ws;

  // ---- fixed ws region ----
  ushort* WembT = (ushort*)(ws + 0);           // 262144
  ushort* WiT   = (ushort*)(ws + 262144);      // -> 1835008
  ushort* WhT   = (ushort*)(ws + 1835008);     // -> 3407872
  ushort* W1T   = (ushort*)(ws + 3407872);     // -> 3932160
  int*    flag  = (int*)   (ws + 3932160);     // 4
  float*  hio   = (float*) (ws + 3936256);     // -> 4460544
  ushort* hbf   = (ushort*)(ws + 4460544);     // 2*256*512*2 = 524288 -> 4984832
  int*    cnt   = (int*)   (ws + 4984832);     // cntL[256] + cntA[256] = 2KB
  int*    xcc   = (int*)   (ws + 5017600);     // 256 ints
  const size_t FIX = 5242880;                  // 5 MiB

  int TC = 0;
  {
    const int cands[6] = {512, 256, 128, 64, 32, 16};
    for(int i = 0; i < 6; i++){
      size_t need = FIX + (size_t)cands[i] * 1310720u;
      if(need <= ws_size){ TC = cands[i]; break; }
    }
  }
  if(TC == 0) return;

  ushort* emb_c  = (ushort*)(ws + FIX);
  ushort* xg_c   = (ushort*)(ws + FIX + (size_t)TC*262144u);
  ushort* ys_c   = (ushort*)(ws + FIX + (size_t)TC*1048576u);
  ushort* crit_c = emb_c;
  ushort* obs_bf = ys_c;   // obs_bf overlaps ys: dead before scan

  k_transpose_bf16<<<(OBSD*DD+255)/256, 256, 0, stream>>>(W_emb, WembT, OBSD, DD);
  k_transpose_bf16<<<(DD*3*DD+255)/256, 256, 0, stream>>>(Wi, WiT, DD, 3*DD);
  k_transpose_bf16<<<(DD*3*DD+255)/256, 256, 0, stream>>>(Wh, WhT, DD, 3*DD);
  k_transpose_bf16<<<(DD*HH+255)/256, 256, 0, stream>>>(W1, W1T, DD, HH);
  k_detect<<<1, 256, 0, stream>>>((const int*)done, flag);

  const int nchunks = TT / TC;
  for(int c = 0; c < nchunks; c++){
    const int Mc = TC * BB;
    const size_t row0 = (size_t)c * Mc;
    k_f32_to_bf16<<<(Mc*OBSD/4 + 255)/256, 256, 0, stream>>>(obs + row0*OBSD, obs_bf,
                                                             Mc*OBSD/4);
    k_gemm128<<<dim3(Mc/128, DD/128), 256, 0, stream>>>(obs_bf, WembT, b_emb,
                                                        emb_c, Mc, DD, OBSD, 1, 0);
    k_gemm128<<<dim3(Mc/128, (3*DD)/128), 256, 0, stream>>>(emb_c, WiT, bi,
                                                            xg_c, Mc, 3*DD, DD, 0, 1);
    {
      const ushort* xg_a = xg_c;  const void* done_a = done;
      const int* flag_a = flag;   const float* hin_a = (c == 0) ? hstate : hio;
      const ushort* wht_a = WhT;  const float* bhn_a = bhn;
      ushort* ys_a = ys_c;        float* hio_a = hio;
      float* hl_a = out;          ushort* hbf_a = hbf;
      int t0_a = c*TC;            int steps_a = TC;
      int* cnt_a = cnt;           int* xcc_a = xcc;
      void* args[14] = { (void*)&xg_a, (void*)&done_a, (void*)&flag_a, (void*)&hin_a,
                         (void*)&wht_a, (void*)&bhn_a, (void*)&ys_a, (void*)&hio_a,
                         (void*)&hl_a, (void*)&hbf_a, (void*)&t0_a, (void*)&steps_a,
                         (void*)&cnt_a, (void*)&xcc_a };
      hipMemsetAsync(cnt, 0, 4096, stream);
      hipError_t err = hipLaunchCooperativeKernel((const void*)k_scan_coop,
                                                  dim3(256), dim3(128), args, 0, stream);
      if(err != hipSuccess){
        k_scan<<<16, 1024, 0, stream>>>(xg_c, done, flag, hin_a, WhT, bhn,
                                        ys_c, hio, out, c*TC, TC);
      }
    }
    k_gemm128<<<dim3(Mc/128, HH/128), 256, 0, stream>>>(ys_c, W1T, b1,
                                                        crit_c, Mc, HH, DD, 1, 0);
    k_value<<<Mc/4, 256, 0, stream>>>(crit_c, W2, b2, out + (size_t)BB*DD + row0);
  }
}

// Round 14
// 2783.462 us; speedup vs baseline: 8.2777x; 1.1199x over previous
//
#include <hip/hip_runtime.h>

// Problem dims
#define TT   512
#define BB   256
#define OBSD 256
#define DD   512
#define HH   512
#define MROWS (TT*BB)   // 131072

typedef __attribute__((ext_vector_type(8))) short short8;
typedef __attribute__((ext_vector_type(4))) float f32x4;

__device__ __forceinline__ ushort f2b(float f){
  unsigned int x = __float_as_uint(f);
  x = (x + 0x7fffu + ((x >> 16) & 1u)) >> 16;   // RNE
  return (ushort)x;
}
__device__ __forceinline__ float b2f(ushort u){
  return __uint_as_float(((unsigned int)u) << 16);
}
__device__ __forceinline__ float sigm(float x){ return 1.f/(1.f + __expf(-x)); }
__device__ __forceinline__ float tanh_f(float x){ return 1.f - 2.f/(__expf(2.f*x) + 1.f); }

// ---------------- transpose f32 [K,N] -> bf16 [N,K] ----------------
__global__ void k_transpose_bf16(const float* __restrict__ W, ushort* __restrict__ Wt,
                                 int K, int N){
  int i = blockIdx.x*256 + threadIdx.x;
  if(i >= K*N) return;
  int k = i / N, n = i % N;
  Wt[(size_t)n*K + k] = f2b(W[i]);
}

// ---------------- f32 -> bf16 elementwise (vectorized) ----------------
__global__ void k_f32_to_bf16(const float* __restrict__ in, ushort* __restrict__ out,
                              int n4){
  int i = blockIdx.x*256 + threadIdx.x;
  if(i >= n4) return;
  const float4 v = ((const float4*)in)[i];
  union{ ushort u[4]; uint2 d; } p;
  p.u[0] = f2b(v.x); p.u[1] = f2b(v.y); p.u[2] = f2b(v.z); p.u[3] = f2b(v.w);
  ((uint2*)out)[i] = p.d;
}

// ---------------- detect done dtype (byte-packed vs 4-byte) ----------------
__global__ void k_detect(const int* __restrict__ done, int* __restrict__ flag){
  __shared__ int cnt;
  if(threadIdx.x == 0) cnt = 0;
  __syncthreads();
  int c = 0;
  for(int i = threadIdx.x; i < 32768; i += 256) c += (done[i] != 0);
  for(int off = 32; off; off >>= 1) c += __shfl_down(c, off, 64);
  if((threadIdx.x & 63) == 0) atomicAdd(&cnt, c);
  __syncthreads();
  if(threadIdx.x == 0) *flag = (cnt > 700) ? 1 : 0;  // 1 => byte-packed bools
}

// ---------------- 128x128-tile MFMA GEMM, 2-phase double-buffered staging ----------------
// vpart != nullptr => critic+value fusion: C is NOT written; instead per-row partial
// dot products with W2f over this block's 128 cols go to vpart[(by*2+wc)*M + row].
#define GSTAGE(buf, k0v) { \
  _Pragma("unroll") \
  for(int j = 0; j < 2; j++){ \
    const int flat = tid*16 + j*4096;        /* byte offset in 8KB tile */ \
    const int rw  = flat >> 6;               /* 64B per row */ \
    const int ke  = (flat & 63) >> 1;        /* k-elem within 32 */ \
    __builtin_amdgcn_global_load_lds( \
      (const __attribute__((address_space(1))) void*)(A + (m0+rw)*(size_t)K + (k0v) + ke), \
      (__attribute__((address_space(3))) void*)((char*)As[buf] + flat), 16, 0, 0); \
    __builtin_amdgcn_global_load_lds( \
      (const __attribute__((address_space(1))) void*)(Bt + (n0+rw)*(size_t)K + (k0v) + ke), \
      (__attribute__((address_space(3))) void*)((char*)Bs[buf] + flat), 16, 0, 0); \
  } }
#define GCOMPUTE(buf) { \
    short8 af[4], bf[4]; \
    _Pragma("unroll") for(int mi=0;mi<4;mi++) \
      af[mi] = *(const short8*)((const char*)As[buf] + (wr*64+mi*16+l16)*64 + l4*16); \
    _Pragma("unroll") for(int ni=0;ni<4;ni++) \
      bf[ni] = *(const short8*)((const char*)Bs[buf] + (wc*64+ni*16+l16)*64 + l4*16); \
    _Pragma("unroll") for(int mi=0;mi<4;mi++) \
      _Pragma("unroll") for(int ni=0;ni<4;ni++) \
        acc[mi][ni] = __builtin_amdgcn_mfma_f32_16x16x32_bf16(af[mi], bf[ni], acc[mi][ni], 0,0,0); }

__global__ __launch_bounds__(256) void k_gemm128(const ushort* __restrict__ A,
                                                 const ushort* __restrict__ Bt,
                                                 const float* __restrict__ bias,
                                                 ushort* __restrict__ C,
                                                 int M, int N, int K, int relu,
                                                 int xg_layout,
                                                 float* __restrict__ vpart,
                                                 const float* __restrict__ W2f){
  __shared__ __align__(16) ushort As[2][4096];   // 2 x 8KB
  __shared__ __align__(16) ushort Bs[2][4096];
  const int tid = threadIdx.x;
  const int l = tid & 63, l16 = l & 15, l4 = l >> 4;
  const int w = tid >> 6, wr = w >> 1, wc = w & 1;
  const size_t m0 = (size_t)blockIdx.x*128, n0 = (size_t)blockIdx.y*128;
  f32x4 acc[4][4] = {};

  GSTAGE(0, 0);
  asm volatile("s_waitcnt vmcnt(0)" ::: "memory");
  __syncthreads();
  int cur = 0;
  for(int k0 = 32; k0 < K; k0 += 32){
    GSTAGE(cur^1, k0);           // prefetch next tile while computing current
    GCOMPUTE(cur);
    asm volatile("s_waitcnt vmcnt(0)" ::: "memory");
    __syncthreads();
    cur ^= 1;
  }
  GCOMPUTE(cur);

  if(vpart){
    // ---- critic+value fusion: partial dots with W2 over this block's cols ----
    float w2v[4];
    float bv[4];
    #pragma unroll
    for(int ni=0;ni<4;ni++){
      const int col = (int)n0 + wc*64 + ni*16 + l16;
      w2v[ni] = W2f[col];
      bv[ni]  = bias[col];
    }
    #pragma unroll
    for(int mi=0;mi<4;mi++){
      #pragma unroll
      for(int r=0;r<4;r++){
        float s = 0.f;
        #pragma unroll
        for(int ni=0;ni<4;ni++){
          float v = acc[mi][ni][r] + bv[ni];
          v = fmaxf(v, 0.f);           // critic relu
          s += v * w2v[ni];
        }
        #pragma unroll
        for(int off=1; off<16; off<<=1) s += __shfl_xor(s, off, 16);
        if(l16 == 0){
          const int row = (int)m0 + wr*64 + mi*16 + l4*4 + r;
          vpart[(size_t)(blockIdx.y*2 + wc)*M + row] = s;
        }
      }
    }
    return;
  }

  #pragma unroll
  for(int ni=0;ni<4;ni++){
    const int col = (int)n0 + wc*64 + ni*16 + l16;
    const float bv = bias[col];
    #pragma unroll
    for(int mi=0;mi<4;mi++){
      #pragma unroll
      for(int r=0;r<4;r++){
        const int row = (int)m0 + wr*64 + mi*16 + l4*4 + r;
        float v = acc[mi][ni][r] + bv;
        if(relu) v = fmaxf(v, 0.f);
        size_t addr;
        if(xg_layout){
          const int tl = row >> 8, brow = row & 255;
          const int gg = brow >> 5, r32 = brow & 31;
          const int gate = col >> 9, cw = col & 511, ds2 = cw >> 4, c16 = cw & 15;
          addr = ((((size_t)tl*32 + ds2)*8 + gg)*3 + gate)*512 + r32*16 + c16;
        } else {
          addr = (size_t)row*N + col;
        }
        C[addr] = f2b(v);
      }
    }
  }
}

// ---------------- value reduce: val[i] = sum_{cb<8} vpart[cb][i] + b2 ----------------
__global__ __launch_bounds__(256) void k_value_reduce(const float* __restrict__ vp,
                                                      const float* __restrict__ b2,
                                                      float* __restrict__ val, int M){
  int i = blockIdx.x*256 + threadIdx.x;
  if(i >= M) return;
  float s = b2[0];
  #pragma unroll
  for(int cb=0; cb<8; cb++) s += vp[(size_t)cb*M + i];
  val[i] = s;
}

// ======================= cooperative GRU scan (r11-proven) =======================
__device__ __forceinline__ void bar_slow(int* cntA, int g, int ds, int target, int tid){
  asm volatile("s_waitcnt vmcnt(0)" ::: "memory");
  __syncthreads();
  if(tid == 0)
    __hip_atomic_store(cntA + g*32 + ds, target,
                       __ATOMIC_RELAXED, __HIP_MEMORY_SCOPE_AGENT);
  if(tid < 32){
    const int* fp = cntA + g*32 + tid;
    while(__hip_atomic_load(fp, __ATOMIC_RELAXED, __HIP_MEMORY_SCOPE_AGENT) < target)
      __builtin_amdgcn_s_sleep(1);
  }
  __syncthreads();
}

__device__ __forceinline__ void bar_fast(int* cntL, int* cntA, int g, int ds,
                                         int target, int tid){
  asm volatile("s_waitcnt vmcnt(0)" ::: "memory");   // h stores landed in local L2
  __syncthreads();
  if(tid == 0){
    int* pL = cntL + g*32 + ds;
    asm volatile("global_atomic_swap %0, %1, off" :: "v"(pL), "v"(target) : "memory");
    __hip_atomic_store(cntA + g*32 + ds, target,
                       __ATOMIC_RELAXED, __HIP_MEMORY_SCOPE_AGENT);   // mirror
  }
  if(tid < 32){
    int* fpL = cntL + g*32 + tid;
    const int* fpA = cntA + g*32 + tid;
    int it = 0;
    for(;;){
      int old;
      asm volatile("global_atomic_add %0, %1, %2, off sc0"
                   : "=v"(old) : "v"(fpL), "v"(0) : "memory");
      asm volatile("s_waitcnt vmcnt(0)" ::: "memory");
      if(old >= target) break;
      if((++it & 15) == 0 &&
         __hip_atomic_load(fpA, __ATOMIC_RELAXED, __HIP_MEMORY_SCOPE_AGENT) >= target)
        break;                                        // safety net: agent mirror
      __builtin_amdgcn_s_sleep(1);
    }
  }
  __syncthreads();
  asm volatile("buffer_inv sc0" ::: "memory");        // L1 invalidate before peer-h reads
}

#define ALD_S(v, j) { const ushort* pj_ = hgrp + (j)*1024; \
  asm volatile("global_load_dwordx4 %0, %1, off sc0 sc1" : "=&v"(v) : "v"(pj_)); }
#define ALD_F(v, j) { const ushort* pj_ = hgrp + (j)*1024; \
  asm volatile("global_load_dwordx4 %0, %1, off" : "=&v"(v) : "v"(pj_)); }
#define DECL_A short8 a0,a1,a2,a3,a4,a5,a6,a7,a8,a9,a10,a11,a12,a13,a14,a15
#define ALOADS(M) M(a0,0);M(a1,1);M(a2,2);M(a3,3);M(a4,4);M(a5,5);M(a6,6);M(a7,7); \
  M(a8,8);M(a9,9);M(a10,10);M(a11,11);M(a12,12);M(a13,13);M(a14,14);M(a15,15)
#define ZERO_A { const short8 z = {0,0,0,0,0,0,0,0}; \
  a0=z;a1=z;a2=z;a3=z;a4=z;a5=z;a6=z;a7=z;a8=z;a9=z;a10=z;a11=z;a12=z;a13=z;a14=z;a15=z; }
#define STEPK(ak, k0lit) { const int kboff = ((k0lit + l4*8) << 1); \
  _Pragma("unroll") for(int gi=0; gi<3; gi++){ \
    const short8 wf = *(const short8*)((const char*)whs + ((rb[gi] + kboff) ^ sw[gi])); \
    acc[gi] = __builtin_amdgcn_mfma_f32_16x16x32_bf16(wf, ak, acc[gi], 0, 0, 0); } }
#define MFMA48 STEPK(a0,0) STEPK(a1,32) STEPK(a2,64) STEPK(a3,96) STEPK(a4,128) \
  STEPK(a5,160) STEPK(a6,192) STEPK(a7,224) STEPK(a8,256) STEPK(a9,288) STEPK(a10,320) \
  STEPK(a11,352) STEPK(a12,384) STEPK(a13,416) STEPK(a14,448) STEPK(a15,480)
#define XG_PREFETCH(tls, nb) { \
  const ushort* slb_ = xg + (((size_t)(tls)*32 + ds)*8 + g)*1536; \
  const int q0_ = m ? 512 : 0; \
  __builtin_amdgcn_global_load_lds( \
    (const __attribute__((address_space(1))) void*)(slb_ + q0_ + l*8), \
    (__attribute__((address_space(3))) void*)(&xgs[nb][q0_]), 16, 0, 0); \
  __builtin_amdgcn_global_load_lds( \
    (const __attribute__((address_space(1))) void*)(slb_ + 1024 + l*8), \
    (__attribute__((address_space(3))) void*)(&xgs[nb][1024]), 16, 0, 0); }
#define GRU_EPI(pv) { \
  const uint2 xru = *(const uint2*)&xgs[cur][        r32*16 + l4*4]; \
  const uint2 xzu = *(const uint2*)&xgs[cur][ 512 +  r32*16 + l4*4]; \
  const uint2 xnu = *(const uint2*)&xgs[cur][1024 +  r32*16 + l4*4]; \
  const ushort xr4[4] = {(ushort)(xru.x&0xffff),(ushort)(xru.x>>16), \
                         (ushort)(xru.y&0xffff),(ushort)(xru.y>>16)}; \
  const ushort xz4[4] = {(ushort)(xzu.x&0xffff),(ushort)(xzu.x>>16), \
                         (ushort)(xzu.y&0xffff),(ushort)(xzu.y>>16)}; \
  const ushort xn4[4] = {(ushort)(xnu.x&0xffff),(ushort)(xnu.x>>16), \
                         (ushort)(xnu.y&0xffff),(ushort)(xnu.y>>16)}; \
  const float bhv[4] = {bh4.x, bh4.y, bh4.z, bh4.w}; \
  union{ ushort u[4]; uint2 v; } p; \
  _Pragma("unroll") for(int r=0;r<4;r++){ \
    const float hold = dn ? 0.f : hf[r]; \
    const float rg = sigm(b2f(xr4[r]) + acc[0][r]); \
    const float zg = sigm(b2f(xz4[r]) + acc[1][r]); \
    const float ng = tanh_f(b2f(xn4[r]) + rg*(acc[2][r] + bhv[r])); \
    const float hv = (1.f - zg)*ng + zg*hold; \
    hf[r] = hv; p.u[r] = f2b(hv); } \
  pv = p.v; }

__global__ __launch_bounds__(128, 1) void k_scan_coop(
    const ushort* __restrict__ xg,        // scan-native layout, chunk-local
    const void* __restrict__ donep,
    const int* __restrict__ flagp, const float* __restrict__ h_in,
    const ushort* __restrict__ WhT, const float* __restrict__ bhn,
    ushort* __restrict__ ys, float* __restrict__ h_io,
    float* __restrict__ h_last, ushort* __restrict__ hbf,   // [2][8g][32ds][32r][16d]
    int t0, int steps, int* __restrict__ cntbase, int* __restrict__ xcc_tab){
  __shared__ __align__(16) ushort whs[48*512];     // 48 KB
  __shared__ __align__(16) ushort xgs[2][1536];    // 6 KB double-buffered xg slice
  __shared__ unsigned char dns[512*32];            // 16 KB done bits for this group
  __shared__ int fastf;
  const int tid = threadIdx.x;
  const int m = tid >> 6, l = tid & 63, l16 = l & 15, l4 = l >> 4;
  const int bid = blockIdx.x;
  const int g = bid & 7, ds = bid >> 3;            // XCD-friendly grouping
  const int use8 = *flagp;
  const unsigned char* d8 = (const unsigned char*)donep;
  const int* d32 = (const int*)donep;
  int* cntL = cntbase;          // 256 ints: L2-local flags
  int* cntA = cntbase + 256;    // 256 ints: agent-scope flags (mirror / slow path)

  // ---- stage WhT slice into LDS, swizzled ----
  for(int e = tid; e < 3072; e += 128){
    const int lr = e >> 6;              // local row 0..47 (gate*16 + d-within-16)
    const int kc = (e & 63) << 3;       // k 0..504 step 8
    const int grow_w = (lr >> 4)*DD + ds*16 + (lr & 15);
    short8 v = *(const short8*)(WhT + (size_t)grow_w*DD + kc);
    int boff = ((lr << 10) + (kc << 1)) ^ ((lr & 7) << 4);
    *(short8*)((char*)whs + boff) = v;
  }
  // ---- stage done bits for this group's 32 rows x steps ----
  for(int e = tid; e < steps*32; e += 128){
    const int tloc = e >> 5, r = e & 31;
    const int gi = (t0 + tloc)*BB + g*32 + r;
    dns[e] = use8 ? (d8[gi] != 0) : (d32[gi] != 0);
  }

  // ---- thread ownership: 1 batch row x 4 consecutive d ----
  const int r32 = m*16 + l16;           // local row index 0..31
  const int row = g*32 + r32;           // batch row
  const int d0  = ds*16 + l4*4;         // first of 4 d outputs
  const float4 bh4 = *(const float4*)(bhn + d0);

  // ---- prologue: load h f32, publish bf16 into hbf[0] (IF-coherent, safe pre-detect) ----
  float hf[4];
  {
    const float4 hv4 = *(const float4*)(h_in + (size_t)row*DD + d0);
    hf[0]=hv4.x; hf[1]=hv4.y; hf[2]=hv4.z; hf[3]=hv4.w;
    union{ ushort u[4]; uint2 v; } p;
    #pragma unroll
    for(int r=0;r<4;r++) p.u[r] = f2b(hf[r]);
    const ushort* pp = hbf + (size_t)g*16384 + ds*512 + r32*16 + l4*4;
    asm volatile("global_store_dwordx2 %0, %1, off sc0 sc1" :: "v"(pp), "v"(p.v) : "memory");
  }
  // ---- stage xg slice for step 0 into xgs[0] ----
  XG_PREFETCH(0, 0);
  // ---- publish own XCC id, exchange via the safe agent barrier ----
  int my_xcc;
  asm volatile("s_getreg_b32 %0, hwreg(HW_REG_XCC_ID)" : "=s"(my_xcc));
  if(tid == 0){
    int* p = xcc_tab + bid;
    asm volatile("global_store_dword %0, %1, off sc0 sc1" :: "v"(p), "v"(my_xcc) : "memory");
  }
  bar_slow(cntA, g, ds, 1, tid);
  {
    int bad = 0;
    if(tid < 32){
      const int* p = xcc_tab + tid*8 + g;   // member bid = tid*8 + g
      int v;
      asm volatile("global_load_dword %0, %1, off sc0 sc1" : "=v"(v) : "v"(p) : "memory");
      asm volatile("s_waitcnt vmcnt(0)" ::: "memory");
      bad = (v != my_xcc);
    }
    const int anybad = __any(bad);
    if(tid == 0) fastf = !anybad;
    __syncthreads();
  }
  const int fast = fastf;

  // wh-frag swizzle bases (gate gi -> local row gi*16 + l16)
  int rb[3], sw[3];
  #pragma unroll
  for(int gi=0; gi<3; gi++){
    const int lr = gi*16 + l16;
    rb[gi] = lr << 10;
    sw[gi] = (lr & 7) << 4;
  }
  const ushort* hb0 = hbf;
  const ushort* hb1 = hbf + (size_t)BB*DD;
  // consumer base within group region: chunk (l4>>1), within-chunk elem (l4&1)*8
  const size_t csub = (size_t)((l4>>1) << 9) + (size_t)r32*16 + ((l4&1) << 3);
  int cur = 0;

  if(fast){
    asm volatile("buffer_inv sc0" ::: "memory");   // pre-loop L1 inv (prologue h via IF)
    for(int tl = 0; tl < steps; tl++){
      const ushort* hcur = (tl & 1) ? hb1 : hb0;
      ushort* hnxt = (ushort*)((tl & 1) ? hb0 : hb1);
      const bool dn = dns[tl*32 + r32];
      const ushort* hgrp = hcur + (size_t)g*16384 + csub;
      DECL_A;
      ALOADS(ALD_F);
      __builtin_amdgcn_sched_barrier(0);
      if(tl + 1 < steps){
        XG_PREFETCH(tl+1, cur^1);               // issued AFTER A-loads
        __builtin_amdgcn_sched_barrier(0);
        asm volatile("s_waitcnt vmcnt(2)" ::: "memory");   // A-loads done, 2 xg in flight
      } else {
        asm volatile("s_waitcnt vmcnt(0)" ::: "memory");
      }
      __builtin_amdgcn_sched_barrier(0);
      if(__builtin_expect(dn, 0)) ZERO_A;
      f32x4 acc[3] = {};
      MFMA48;
      uint2 pv;
      GRU_EPI(pv);
      const ushort* pp = hnxt + (size_t)g*16384 + ds*512 + r32*16 + l4*4;
      asm volatile("global_store_dwordx2 %0, %1, off" :: "v"(pp), "v"(pv) : "memory");
      bar_fast(cntL, cntA, g, ds, tl + 2, tid);  // vmcnt(0): xg landed during MFMA
      *(uint2*)(ys + ((size_t)tl*BB + row)*DD + d0) = pv;
      cur ^= 1;
    }
  } else {
    for(int tl = 0; tl < steps; tl++){
      const ushort* hcur = (tl & 1) ? hb1 : hb0;
      ushort* hnxt = (ushort*)((tl & 1) ? hb0 : hb1);
      const bool dn = dns[tl*32 + r32];
      const ushort* hgrp = hcur + (size_t)g*16384 + csub;
      DECL_A;
      ALOADS(ALD_S);
      __builtin_amdgcn_sched_barrier(0);
      if(tl + 1 < steps){
        XG_PREFETCH(tl+1, cur^1);
        __builtin_amdgcn_sched_barrier(0);
        asm volatile("s_waitcnt vmcnt(2)" ::: "memory");
      } else {
        asm volatile("s_waitcnt vmcnt(0)" ::: "memory");
      }
      __builtin_amdgcn_sched_barrier(0);
      if(__builtin_expect(dn, 0)) ZERO_A;
      f32x4 acc[3] = {};
      MFMA48;
      uint2 pv;
      GRU_EPI(pv);
      const ushort* pp = hnxt + (size_t)g*16384 + ds*512 + r32*16 + l4*4;
      asm volatile("global_store_dwordx2 %0, %1, off sc0 sc1" :: "v"(pp), "v"(pv) : "memory");
      bar_slow(cntA, g, ds, tl + 2, tid);
      *(uint2*)(ys + ((size_t)tl*BB + row)*DD + d0) = pv;
      cur ^= 1;
    }
  }

  {
    float4 o; o.x=hf[0]; o.y=hf[1]; o.z=hf[2]; o.w=hf[3];
    *(float4*)(h_io   + (size_t)row*DD + d0) = o;
    *(float4*)(h_last + (size_t)row*DD + d0) = o;
  }
}

// ---------------- fallback GRU scan (16 blocks; scan-native xg layout) ----------------
__global__ __launch_bounds__(1024) void k_scan(const ushort* __restrict__ xg,
                                               const void* __restrict__ donep,
                                               const int* __restrict__ flagp,
                                               const float* __restrict__ h_in,
                                               const ushort* __restrict__ WhT,
                                               const float* __restrict__ bhn,
                                               ushort* __restrict__ ys,
                                               float* __restrict__ h_io,
                                               float* __restrict__ h_last,
                                               int t0, int steps){
  __shared__ __align__(16) float  h_f[16][DD];
  __shared__ __align__(16) ushort h_b[16][DD];
  const int tid = threadIdx.x;
  const int w = tid >> 6, l = tid & 63, l16 = l & 15, l4 = l >> 4;
  const int b0 = blockIdx.x * 16;
  const int use8 = *flagp;
  const unsigned char* d8 = (const unsigned char*)donep;
  const int* d32 = (const int*)donep;

  for(int e = tid; e < 16*DD; e += 1024){
    int b = e >> 9, dd = e & (DD-1);
    float v = h_in[(size_t)(b0 + b)*DD + dd];
    h_f[b][dd] = v; h_b[b][dd] = f2b(v);
  }
  __syncthreads();

  const int dbase = w * 32;
  const ushort* bp[6];
  #pragma unroll
  for(int g=0; g<3; g++)
    #pragma unroll
    for(int nt=0; nt<2; nt++)
      bp[g*2+nt] = WhT + (size_t)(g*DD + dbase + nt*16 + l16) * DD;

  for(int tl = 0; tl < steps; tl++){
    const int drow = (t0 + tl)*BB + b0;
    const bool dnA = use8 ? (d8[drow + l16] != 0) : (d32[drow + l16] != 0);
    f32x4 acc[3][2] = {};
    const short8 zf = {0,0,0,0,0,0,0,0};
    for(int k0 = 0; k0 < DD; k0 += 32){
      const int kb = k0 + l4*8;
      short8 a = *(const short8*)&h_b[l16][kb];
      if(dnA) a = zf;
      #pragma unroll
      for(int g=0; g<3; g++)
        #pragma unroll
        for(int nt=0; nt<2; nt++){
          const short8 b = *(const short8*)(bp[g*2+nt] + kb);
          acc[g][nt] = __builtin_amdgcn_mfma_f32_16x16x32_bf16(a, b, acc[g][nt], 0, 0, 0);
        }
    }
    float hnew[2][4];
    #pragma unroll
    for(int nt=0; nt<2; nt++){
      const int dd = dbase + nt*16 + l16;
      const float bh = bhn[dd];
      const int ds2 = dd >> 4, c16 = dd & 15;
      #pragma unroll
      for(int r=0; r<4; r++){
        const int brow = l4*4 + r;
        const int grow = b0 + brow;
        const int gg = grow >> 5, r32 = grow & 31;
        const bool dn = use8 ? (d8[drow + brow] != 0) : (d32[drow + brow] != 0);
        const size_t sbase = (((size_t)tl*32 + ds2)*8 + gg)*1536 + r32*16 + c16;
        const float xr = b2f(xg[sbase]);
        const float xz = b2f(xg[sbase + 512]);
        const float xn = b2f(xg[sbase + 1024]);
        const float hold = dn ? 0.f : h_f[brow][dd];
        const float rg = sigm(xr + acc[0][nt][r]);
        const float zg = sigm(xz + acc[1][nt][r]);
        const float ng = tanh_f(xn + rg*(acc[2][nt][r] + bh));
        hnew[nt][r] = (1.f - zg)*ng + zg*hold;
      }
    }
    __syncthreads();
    #pragma unroll
    for(int nt=0; nt<2; nt++){
      const int dd = dbase + nt*16 + l16;
      #pragma unroll
      for(int r=0; r<4; r++){
        const int brow = l4*4 + r;
        const size_t rowl = (size_t)(tl*BB + b0 + brow);
        const float hv = hnew[nt][r];
        h_f[brow][dd] = hv;
        h_b[brow][dd] = f2b(hv);
        ys[rowl*DD + dd] = f2b(hv);
      }
    }
    __syncthreads();
  }

  for(int e = tid; e < 16*DD; e += 1024){
    int b = e >> 9, dd = e & (DD-1);
    float v = h_f[b][dd];
    h_io[(size_t)(b0 + b)*DD + dd] = v;
    h_last[(size_t)(b0 + b)*DD + dd] = v;
  }
}

extern "C" void kernel_launch(void* const* d_in, const int* in_sizes, int n_in,
                              void* d_out, int out_size, void* d_ws, size_t ws_size,
                              hipStream_t stream){
  const float* obs    = (const float*)d_in[0];
  const void*  done   = d_in[1];
  const float* hstate = (const float*)d_in[2];
  const float* W_emb  = (const float*)d_in[3];
  const float* b_emb  = (const float*)d_in[4];
  const float* Wi     = (const float*)d_in[5];
  const float* bi     = (const float*)d_in[6];
  const float* Wh     = (const float*)d_in[7];
  const float* bhn    = (const float*)d_in[8];
  const float* W1     = (const float*)d_in[9];
  const float* b1     = (const float*)d_in[10];
  const float* W2     = (const float*)d_in[11];
  const float* b2     = (const float*)d_in[12];
  float* out = (float*)d_out;
  char*  ws  = (char*)d_ws;

  // ---- fixed ws region ----
  ushort* WembT = (ushort*)(ws + 0);           // 262144
  ushort* WiT   = (ushort*)(ws + 262144);      // -> 1835008
  ushort* WhT   = (ushort*)(ws + 1835008);     // -> 3407872
  ushort* W1T   = (ushort*)(ws + 3407872);     // -> 3932160
  int*    flag  = (int*)   (ws + 3932160);     // 4
  float*  hio   = (float*) (ws + 3936256);     // -> 4460544
  ushort* hbf   = (ushort*)(ws + 4460544);     // 2*256*512*2 = 524288 -> 4984832
  int*    cnt   = (int*)   (ws + 4984832);     // cntL[256] + cntA[256] = 2KB
  int*    xcc   = (int*)   (ws + 5017600);     // 256 ints
  const size_t FIX = 5242880;                  // 5 MiB

  int TC = 0;
  {
    const int cands[6] = {512, 256, 128, 64, 32, 16};
    for(int i = 0; i < 6; i++){
      size_t need = FIX + (size_t)cands[i] * 1310720u;
      if(need <= ws_size){ TC = cands[i]; break; }
    }
  }
  if(TC == 0) return;

  ushort* emb_c  = (ushort*)(ws + FIX);
  ushort* xg_c   = (ushort*)(ws + FIX + (size_t)TC*262144u);
  ushort* ys_c   = (ushort*)(ws + FIX + (size_t)TC*1048576u);
  float*  vpart  = (float*)emb_c;   // 8 * Mc * 4B <= TC*262144 B: fits (emb dead)
  ushort* obs_bf = ys_c;            // obs_bf overlaps ys: dead before scan

  k_transpose_bf16<<<(OBSD*DD+255)/256, 256, 0, stream>>>(W_emb, WembT, OBSD, DD);
  k_transpose_bf16<<<(DD*3*DD+255)/256, 256, 0, stream>>>(Wi, WiT, DD, 3*DD);
  k_transpose_bf16<<<(DD*3*DD+255)/256, 256, 0, stream>>>(Wh, WhT, DD, 3*DD);
  k_transpose_bf16<<<(DD*HH+255)/256, 256, 0, stream>>>(W1, W1T, DD, HH);
  k_detect<<<1, 256, 0, stream>>>((const int*)done, flag);

  const int nchunks = TT / TC;
  for(int c = 0; c < nchunks; c++){
    const int Mc = TC * BB;
    const size_t row0 = (size_t)c * Mc;
    k_f32_to_bf16<<<(Mc*OBSD/4 + 255)/256, 256, 0, stream>>>(obs + row0*OBSD, obs_bf,
                                                             Mc*OBSD/4);
    k_gemm128<<<dim3(Mc/128, DD/128), 256, 0, stream>>>(obs_bf, WembT, b_emb,
                                                        emb_c, Mc, DD, OBSD, 1, 0,
                                                        nullptr, nullptr);
    k_gemm128<<<dim3(Mc/128, (3*DD)/128), 256, 0, stream>>>(emb_c, WiT, bi,
                                                            xg_c, Mc, 3*DD, DD, 0, 1,
                                                            nullptr, nullptr);
    {
      const ushort* xg_a = xg_c;  const void* done_a = done;
      const int* flag_a = flag;   const float* hin_a = (c == 0) ? hstate : hio;
      const ushort* wht_a = WhT;  const float* bhn_a = bhn;
      ushort* ys_a = ys_c;        float* hio_a = hio;
      float* hl_a = out;          ushort* hbf_a = hbf;
      int t0_a = c*TC;            int steps_a = TC;
      int* cnt_a = cnt;           int* xcc_a = xcc;
      void* args[14] = { (void*)&xg_a, (void*)&done_a, (void*)&flag_a, (void*)&hin_a,
                         (void*)&wht_a, (void*)&bhn_a, (void*)&ys_a, (void*)&hio_a,
                         (void*)&hl_a, (void*)&hbf_a, (void*)&t0_a, (void*)&steps_a,
                         (void*)&cnt_a, (void*)&xcc_a };
      hipMemsetAsync(cnt, 0, 4096, stream);
      hipError_t err = hipLaunchCooperativeKernel((const void*)k_scan_coop,
                                                  dim3(256), dim3(128), args, 0, stream);
      if(err != hipSuccess){
        k_scan<<<16, 1024, 0, stream>>>(xg_c, done, flag, hin_a, WhT, bhn,
                                        ys_c, hio, out, c*TC, TC);
      }
    }
    // critic GEMM with fused value partial-dots (critic never materialized)
    k_gemm128<<<dim3(Mc/128, HH/128), 256, 0, stream>>>(ys_c, W1T, b1,
                                                        nullptr, Mc, HH, DD, 1, 0,
                                                        vpart, W2);
    k_value_reduce<<<(Mc + 255)/256, 256, 0, stream>>>(vpart, b2,
                                                       out + (size_t)BB*DD + row0, Mc);
  }
}